// Round 30
// baseline (4158.372 us; speedup 1.0000x reference)
//
#include <hip/hip_runtime.h>
#include <math.h>

// Problem constants
#define TT   48
#define BB   32
#define CINC 2
#define CR   64
#define HH   34
#define WW   34
#define HWW  (HH*WW)        // 1156
#define PWP  36
#define PHWP (36*36)        // 1296 padded plane
#define NOUT 10
#define NP   3
#define OG   4              // output channels per block (64/OG = 16 groups)
#define RCH  6              // readout_conv chunks (192 pc / 32 each)

// ---------------------------------------------------------------------------
// One-time weight transpose (pure copies, no FP arithmetic -> exact):
//   wrT[(tap*64+ci)*64 + o] = w_rec[o*576 + ci*9 + tap]
//   wiT[(tap*2 +ci)*64 + o] = w_in [o*18  + ci*9 + tap]
// ---------------------------------------------------------------------------
__global__ __launch_bounds__(256) void transpose_weights(
    const float* __restrict__ w_in,  // [64,2,3,3]
    const float* __restrict__ w_rec, // [64,64,3,3]
    float* __restrict__ wiT,         // [18*64]
    float* __restrict__ wrT)         // [576*64]
{
    const int i = blockIdx.x*256 + threadIdx.x;
    if (i < 576*64) {
        const int k = i >> 6, o = i & 63;
        const int tap = k >> 6, ci = k & 63;
        wrT[i] = w_rec[o*576 + ci*9 + tap];
    }
    if (i < 18*64) {
        const int k = i >> 6, o = i & 63;
        const int tap = k >> 1, ci = k & 1;
        wiT[i] = w_in[o*18 + ci*9 + tap];
    }
}

// ---------------------------------------------------------------------------
// Per-timestep LIF step, fp32 — verified reference rounding (R27):
//   conv chains: (kh, kw, ci) ascending, single fmaf chain per (o,pixel),
//   unsplit, bias after; LIF: fma(0.9,syn,cur)+rec, fma(0.9,mem,sv)-reset.
// Thread = pixel, block = (b, ptile, o-group of OG=4). Each spike load is
// reused across OG chains; 9248 waves (~9/SIMD) for latency hiding.
// Chains remain bitwise identical to R27.
// Grid: (BB, 5, 64/OG) x 256 threads.
// ---------------------------------------------------------------------------
__global__ __launch_bounds__(256) void step_kernel(
    const float* __restrict__ x,        // [T,B,2,34,34]
    const float* __restrict__ wiT,      // [18*64] transposed
    const float* __restrict__ b_in,     // [64]
    const float* __restrict__ wrT,      // [576*64] transposed
    const float* __restrict__ b_rec,    // [64]
    const float* __restrict__ sp_rd,    // [B,64,36,36] prev spikes, zero halo
    float*       __restrict__ sp_wr,    // [B,64,36,36] next spikes
    float* __restrict__ syn,            // [B,64,1156]
    float* __restrict__ mem,            // [B,64,1156]
    float* __restrict__ spk_rec,        // [T,B,64,1156] (d_out + 320)
    unsigned char* __restrict__ partsum,// [3,B,64,1156] exact counts <=16
    int t)
{
    #pragma clang fp contract(off)

    const int p = blockIdx.y*256 + threadIdx.x;
    if (p >= HWW) return;
    const int b  = blockIdx.x;
    const int og = blockIdx.z * OG;
    const int part = t >> 4;
    const int h = p / WW;
    const int w = p - h*WW;

    const float* xb  = x + (size_t)((t*BB + b)*CINC)*HWW;
    const float* spb = sp_rd + (size_t)b*CR*PHWP;

    // ---- input conv: per-o chain = (kh,kw,ci) asc fmaf (OOB skip exact) ----
    float cin[OG];
    #pragma unroll
    for (int j = 0; j < OG; ++j) cin[j] = 0.0f;
    #pragma unroll
    for (int kh = 0; kh < 3; ++kh) {
        const int ih = h + kh - 1;
        if ((unsigned)ih >= (unsigned)HH) continue;
        #pragma unroll
        for (int kw = 0; kw < 3; ++kw) {
            const int iw = w + kw - 1;
            if ((unsigned)iw >= (unsigned)WW) continue;
            #pragma unroll
            for (int ci = 0; ci < CINC; ++ci) {
                const float s = xb[ci*HWW + ih*WW + iw];
                const float* wr = wiT + ((kh*3+kw)*2 + ci)*64 + og;
                #pragma unroll
                for (int j = 0; j < OG; ++j)
                    cin[j] = fmaf(wr[j], s, cin[j]);
            }
        }
    }

    // ---- recurrent conv: per-o chain = (tap, ci) asc fmaf, unsplit ----
    float acc[OG];
    #pragma unroll
    for (int j = 0; j < OG; ++j) acc[j] = 0.0f;
    const float* sp0 = spb + h*PWP + w;   // padded (h,w) == orig (h-1,w-1)
    #pragma unroll 1
    for (int tap = 0; tap < 9; ++tap) {
        const int kh = tap / 3;
        const int kw = tap - kh*3;
        const float* sp_t = sp0 + kh*PWP + kw;
        const float* wbase = wrT + (size_t)tap*64*64 + og;
        #pragma unroll 8
        for (int ci = 0; ci < CR; ++ci) {
            const float s = sp_t[(size_t)ci*PHWP];
            const float* wr = wbase + ci*64;
            #pragma unroll
            for (int j = 0; j < OG; ++j)
                acc[j] = fmaf(wr[j], s, acc[j]);
        }
    }

    // ---- LIF per o: verified FMA-contracted form ----
    #pragma unroll
    for (int j = 0; j < OG; ++j) {
        const int o = og + j;
        const size_t so = ((size_t)b*CR + o)*HWW + p;
        const float cur = cin[j] + b_in[o];       // bias after (own rounding)
        const float rec = acc[j] + b_rec[o];
        const float syn_v = syn[so];
        const float m     = mem[so];
        const float sv = fmaf(0.9f, syn_v, cur) + rec;
        const float reset = (m > 1.0f) ? 1.0f : 0.0f;
        const float mn = fmaf(0.9f, m, sv) - reset;
        const int fire = (mn > 1.0f) ? 1 : 0;
        const float sk = (float)fire;

        syn[so] = sv;
        mem[so] = mn;
        spk_rec[((size_t)(t*BB + b)*CR + o)*HWW + p] = sk;
        sp_wr[((size_t)b*CR + o)*PHWP + (h+1)*PWP + (w+1)] = sk;
        unsigned char* ps = partsum + ((size_t)(part*BB + b)*CR + o)*HWW + p;
        *ps = (unsigned char)(*ps + fire);
    }
}

// ---------------------------------------------------------------------------
// Readout conv, fp64, chunked over grid.z (order-insensitive in f64):
// chunk z handles pc in [z*32, z*32+32); partial sums (no bias) to y1p.
// Grid: (B, 5, RCH) x 256 threads.
// ---------------------------------------------------------------------------
__global__ __launch_bounds__(256) void readout_conv_part(
    const unsigned char* __restrict__ partsum, // [3,B,64,1156]
    const float* __restrict__ w_r1,            // [10,192,3,3]
    double* __restrict__ y1p)                  // [RCH,B,10,1156]
{
    const int b = blockIdx.x;
    const int p = blockIdx.y * 256 + threadIdx.x;
    if (p >= HWW) return;
    const int z = blockIdx.z;
    const int h = p / WW;
    const int w = p - h*WW;

    double acc[NOUT];
    #pragma unroll
    for (int j = 0; j < NOUT; ++j) acc[j] = 0.0;

    const int pc0 = z * (NP*CR/RCH);
    for (int pc = pc0; pc < pc0 + NP*CR/RCH; ++pc) {  // pc = part*64 + c
        const int part = pc >> 6;
        const int c    = pc & 63;
        const unsigned char* src =
            partsum + ((size_t)(part*BB + b)*CR + c)*HWW;

        double v[9];
        #pragma unroll
        for (int kh = 0; kh < 3; ++kh) {
            const int ih = h + kh - 1;
            #pragma unroll
            for (int kw = 0; kw < 3; ++kw) {
                const int iw = w + kw - 1;
                const bool ok = ((unsigned)ih < (unsigned)HH) &&
                                ((unsigned)iw < (unsigned)WW);
                v[kh*3+kw] = ok ? (double)src[ih*WW + iw] * 0.0625 : 0.0;
            }
        }
        #pragma unroll
        for (int j = 0; j < NOUT; ++j) {
            const float* wj = w_r1 + ((size_t)j*NP*CR + pc)*9;
            #pragma unroll
            for (int k = 0; k < 9; ++k)
                acc[j] = fma((double)wj[k], v[k], acc[j]);
        }
    }
    #pragma unroll
    for (int j = 0; j < NOUT; ++j)
        y1p[(((size_t)z*BB + b)*NOUT + j)*HWW + p] = acc[j];
}

// Reduce partials + bias -> y1. Grid: (B,5) x 256.
__global__ __launch_bounds__(256) void readout_conv_reduce(
    const double* __restrict__ y1p,   // [RCH,B,10,1156]
    const float* __restrict__ b_r1,   // [10]
    double* __restrict__ y1)          // [B,10,1156]
{
    const int b = blockIdx.x;
    const int p = blockIdx.y * 256 + threadIdx.x;
    if (p >= HWW) return;
    #pragma unroll
    for (int j = 0; j < NOUT; ++j) {
        double s = (double)b_r1[j];
        #pragma unroll
        for (int z = 0; z < RCH; ++z)
            s += y1p[(((size_t)z*BB + b)*NOUT + j)*HWW + p];
        y1[((size_t)b*NOUT + j)*HWW + p] = s;
    }
}

// ---------------------------------------------------------------------------
// FC + softmax in fp64. Grid: B blocks.
// ---------------------------------------------------------------------------
__global__ __launch_bounds__(256) void readout_fc(
    const double* __restrict__ y1,    // [B, 10*1156]
    const float* __restrict__ w_r2,   // [10, 11560]
    const float* __restrict__ b_r2,   // [10]
    float* __restrict__ out)          // [B,10]
{
    const int b = blockIdx.x;
    const double* yb = y1 + (size_t)b*NOUT*HWW;

    double acc[NOUT];
    #pragma unroll
    for (int o = 0; o < NOUT; ++o) acc[o] = 0.0;

    for (int i = threadIdx.x; i < NOUT*HWW; i += 256) {
        const double v = yb[i];
        #pragma unroll
        for (int o = 0; o < NOUT; ++o)
            acc[o] = fma(v, (double)w_r2[(size_t)o*NOUT*HWW + i], acc[o]);
    }

    const int lane = threadIdx.x & 63;
    const int wv   = threadIdx.x >> 6;
    __shared__ double wsum[4][NOUT];

    #pragma unroll
    for (int o = 0; o < NOUT; ++o) {
        double v = acc[o];
        #pragma unroll
        for (int off = 32; off > 0; off >>= 1) v += __shfl_down(v, off);
        if (lane == 0) wsum[wv][o] = v;
    }
    __syncthreads();

    if (threadIdx.x == 0) {
        double s[NOUT];
        double mx = -1e300;
        #pragma unroll
        for (int o = 0; o < NOUT; ++o) {
            s[o] = wsum[0][o] + wsum[1][o] + wsum[2][o] + wsum[3][o]
                 + (double)b_r2[o];
            mx = fmax(mx, s[o]);
        }
        double den = 0.0;
        #pragma unroll
        for (int o = 0; o < NOUT; ++o) { s[o] = exp(s[o] - mx); den += s[o]; }
        #pragma unroll
        for (int o = 0; o < NOUT; ++o) out[b*NOUT + o] = (float)(s[o] / den);
    }
}

// ---------------------------------------------------------------------------
extern "C" void kernel_launch(void* const* d_in, const int* in_sizes, int n_in,
                              void* d_out, int out_size, void* d_ws, size_t ws_size,
                              hipStream_t stream)
{
    const float* x     = (const float*)d_in[0];
    const float* w_in  = (const float*)d_in[1];
    const float* b_in  = (const float*)d_in[2];
    const float* w_rec = (const float*)d_in[3];
    const float* b_rec = (const float*)d_in[4];
    const float* w_r1  = (const float*)d_in[5];
    const float* b_r1  = (const float*)d_in[6];
    const float* w_r2  = (const float*)d_in[7];
    const float* b_r2  = (const float*)d_in[8];

    float* out     = (float*)d_out;          // [32,10]
    float* spk_rec = out + BB*NOUT;          // [48,32,64,34,34]

    // Workspace: syn|mem|pad0|pad1|partsum contiguous -> one zeroing memset.
    const size_t n_state = (size_t)BB*CR*HWW;       // 2,367,488
    const size_t n_pad   = (size_t)BB*CR*PHWP;      // 2,654,208
    const size_t n_part  = (size_t)NP*BB*CR*HWW;    // 7,102,464 bytes (uint8)
    const size_t n_y1    = (size_t)BB*NOUT*HWW;     // 369,920

    char* ws = (char*)d_ws;
    float*         syn     = (float*)ws;             ws += n_state*4;
    float*         mem     = (float*)ws;             ws += n_state*4;
    float*         pad0    = (float*)ws;             ws += n_pad*4;
    float*         pad1    = (float*)ws;             ws += n_pad*4;
    unsigned char* partsum = (unsigned char*)ws;     ws += n_part;
    double*        y1      = (double*)ws;            ws += n_y1*8;
    double*        y1p     = (double*)ws;            ws += (size_t)RCH*n_y1*8;
    float*         wiT     = (float*)ws;             ws += 18*64*4;
    float*         wrT     = (float*)ws;             ws += 576*64*4;

    const size_t zero_bytes = n_state*8 + n_pad*8 + n_part;
    hipMemsetAsync(d_ws, 0, zero_bytes, stream);

    transpose_weights<<<(576*64 + 255)/256, 256, 0, stream>>>(
        w_in, w_rec, wiT, wrT);

    for (int t = 0; t < TT; ++t) {
        const float* rd = (t & 1) ? pad1 : pad0;   // t=0 reads zeroed pad0
        float*       wr = (t & 1) ? pad0 : pad1;
        step_kernel<<<dim3(BB, 5, CR/OG), 256, 0, stream>>>(
            x, wiT, b_in, wrT, b_rec,
            rd, wr, syn, mem, spk_rec, partsum, t);
    }

    readout_conv_part<<<dim3(BB, 5, RCH), 256, 0, stream>>>(partsum, w_r1, y1p);
    readout_conv_reduce<<<dim3(BB, 5), 256, 0, stream>>>(y1p, b_r1, y1);
    readout_fc<<<BB, 256, 0, stream>>>(y1, w_r2, b_r2, out);
}

// Round 31
// 2732.468 us; speedup vs baseline: 1.5218x; 1.5218x over previous
//
#include <hip/hip_runtime.h>
#include <math.h>

// Problem constants
#define TT   48
#define BB   32
#define CINC 2
#define CR   64
#define HH   34
#define WW   34
#define HWW  (HH*WW)        // 1156
#define PWP  36
#define PHWP (36*36)        // 1296 padded plane
#define NOUT 10
#define NP   3
#define OG   8              // output channels per block (64/OG = 8 groups)
#define RCH  6              // readout_conv chunks (192 pc / 32 each)

// ---------------------------------------------------------------------------
// One-time weight transpose (pure copies, no FP arithmetic -> exact):
//   wrT[(tap*64+ci)*64 + o] = w_rec[o*576 + ci*9 + tap]
//   wiT[(tap*2 +ci)*64 + o] = w_in [o*18  + ci*9 + tap]
// ---------------------------------------------------------------------------
__global__ __launch_bounds__(256) void transpose_weights(
    const float* __restrict__ w_in,  // [64,2,3,3]
    const float* __restrict__ w_rec, // [64,64,3,3]
    float* __restrict__ wiT,         // [18*64]
    float* __restrict__ wrT)         // [576*64]
{
    const int i = blockIdx.x*256 + threadIdx.x;
    if (i < 576*64) {
        const int k = i >> 6, o = i & 63;
        const int tap = k >> 6, ci = k & 63;
        wrT[i] = w_rec[o*576 + ci*9 + tap];
    }
    if (i < 18*64) {
        const int k = i >> 6, o = i & 63;
        const int tap = k >> 1, ci = k & 1;
        wiT[i] = w_in[o*18 + ci*9 + tap];
    }
}

// ---------------------------------------------------------------------------
// Per-timestep LIF step, fp32 — verified reference rounding (R27):
//   conv chains: (kh, kw, ci) ascending, single fmaf chain per (o,pixel),
//   unsplit, bias after; LIF: fma(0.9,syn,cur)+rec, fma(0.9,mem,sv)-reset.
// Spike ring buffers are uint8 (0/1): (float)u8 is exact, so
// fmaf(w,(float)s,acc) is bitwise-identical to the reference chain while
// cutting L2 spike traffic 4x (2.65 MB state fits one XCD L2).
// Grid: (BB, 5, 64/OG) x 256 threads; thread = pixel.
// ---------------------------------------------------------------------------
__global__ __launch_bounds__(256) void step_kernel(
    const float* __restrict__ x,        // [T,B,2,34,34]
    const float* __restrict__ wiT,      // [18*64] transposed
    const float* __restrict__ b_in,     // [64]
    const float* __restrict__ wrT,      // [576*64] transposed
    const float* __restrict__ b_rec,    // [64]
    const unsigned char* __restrict__ sp_rd, // [B,64,36,36] prev spikes u8
    unsigned char*       __restrict__ sp_wr, // [B,64,36,36] next spikes u8
    float* __restrict__ syn,            // [B,64,1156]
    float* __restrict__ mem,            // [B,64,1156]
    float* __restrict__ spk_rec,        // [T,B,64,1156] (d_out + 320)
    unsigned char* __restrict__ partsum,// [3,B,64,1156] exact counts <=16
    int t)
{
    #pragma clang fp contract(off)

    const int p = blockIdx.y*256 + threadIdx.x;
    if (p >= HWW) return;
    const int b  = blockIdx.x;
    const int og = blockIdx.z * OG;
    const int part = t >> 4;
    const int h = p / WW;
    const int w = p - h*WW;

    const float* xb = x + (size_t)((t*BB + b)*CINC)*HWW;
    const unsigned char* spb = sp_rd + (size_t)b*CR*PHWP;

    // ---- input conv: per-o chain = (kh,kw,ci) asc fmaf (OOB skip exact) ----
    float cin[OG];
    #pragma unroll
    for (int j = 0; j < OG; ++j) cin[j] = 0.0f;
    #pragma unroll
    for (int kh = 0; kh < 3; ++kh) {
        const int ih = h + kh - 1;
        if ((unsigned)ih >= (unsigned)HH) continue;
        #pragma unroll
        for (int kw = 0; kw < 3; ++kw) {
            const int iw = w + kw - 1;
            if ((unsigned)iw >= (unsigned)WW) continue;
            #pragma unroll
            for (int ci = 0; ci < CINC; ++ci) {
                const float s = xb[ci*HWW + ih*WW + iw];
                const float* wr = wiT + ((kh*3+kw)*2 + ci)*64 + og;
                #pragma unroll
                for (int j = 0; j < OG; ++j)
                    cin[j] = fmaf(wr[j], s, cin[j]);
            }
        }
    }

    // ---- recurrent conv: per-o chain = (tap, ci) asc fmaf, unsplit ----
    float acc[OG];
    #pragma unroll
    for (int j = 0; j < OG; ++j) acc[j] = 0.0f;
    const unsigned char* sp0 = spb + h*PWP + w;  // padded (h,w)=orig(h-1,w-1)
    #pragma unroll 1
    for (int tap = 0; tap < 9; ++tap) {
        const int kh = tap / 3;
        const int kw = tap - kh*3;
        const unsigned char* sp_t = sp0 + kh*PWP + kw;
        const float* wbase = wrT + (size_t)tap*64*64 + og;
        #pragma unroll 8
        for (int ci = 0; ci < CR; ++ci) {
            const float s = (float)sp_t[(size_t)ci*PHWP];  // exact 0/1
            const float* wr = wbase + ci*64;
            #pragma unroll
            for (int j = 0; j < OG; ++j)
                acc[j] = fmaf(wr[j], s, acc[j]);
        }
    }

    // ---- LIF per o: verified FMA-contracted form ----
    #pragma unroll
    for (int j = 0; j < OG; ++j) {
        const int o = og + j;
        const size_t so = ((size_t)b*CR + o)*HWW + p;
        const float cur = cin[j] + b_in[o];       // bias after (own rounding)
        const float rec = acc[j] + b_rec[o];
        const float syn_v = syn[so];
        const float m     = mem[so];
        const float sv = fmaf(0.9f, syn_v, cur) + rec;
        const float reset = (m > 1.0f) ? 1.0f : 0.0f;
        const float mn = fmaf(0.9f, m, sv) - reset;
        const int fire = (mn > 1.0f) ? 1 : 0;

        syn[so] = sv;
        mem[so] = mn;
        spk_rec[((size_t)(t*BB + b)*CR + o)*HWW + p] = (float)fire;
        sp_wr[((size_t)b*CR + o)*PHWP + (h+1)*PWP + (w+1)] =
            (unsigned char)fire;
        unsigned char* ps = partsum + ((size_t)(part*BB + b)*CR + o)*HWW + p;
        *ps = (unsigned char)(*ps + fire);
    }
}

// ---------------------------------------------------------------------------
// Readout conv, fp64, chunked over grid.z (order-insensitive in f64):
// chunk z handles pc in [z*32, z*32+32); partial sums (no bias) to y1p.
// Grid: (B, 5, RCH) x 256 threads.
// ---------------------------------------------------------------------------
__global__ __launch_bounds__(256) void readout_conv_part(
    const unsigned char* __restrict__ partsum, // [3,B,64,1156]
    const float* __restrict__ w_r1,            // [10,192,3,3]
    double* __restrict__ y1p)                  // [RCH,B,10,1156]
{
    const int b = blockIdx.x;
    const int p = blockIdx.y * 256 + threadIdx.x;
    if (p >= HWW) return;
    const int z = blockIdx.z;
    const int h = p / WW;
    const int w = p - h*WW;

    double acc[NOUT];
    #pragma unroll
    for (int j = 0; j < NOUT; ++j) acc[j] = 0.0;

    const int pc0 = z * (NP*CR/RCH);
    for (int pc = pc0; pc < pc0 + NP*CR/RCH; ++pc) {  // pc = part*64 + c
        const int part = pc >> 6;
        const int c    = pc & 63;
        const unsigned char* src =
            partsum + ((size_t)(part*BB + b)*CR + c)*HWW;

        double v[9];
        #pragma unroll
        for (int kh = 0; kh < 3; ++kh) {
            const int ih = h + kh - 1;
            #pragma unroll
            for (int kw = 0; kw < 3; ++kw) {
                const int iw = w + kw - 1;
                const bool ok = ((unsigned)ih < (unsigned)HH) &&
                                ((unsigned)iw < (unsigned)WW);
                v[kh*3+kw] = ok ? (double)src[ih*WW + iw] * 0.0625 : 0.0;
            }
        }
        #pragma unroll
        for (int j = 0; j < NOUT; ++j) {
            const float* wj = w_r1 + ((size_t)j*NP*CR + pc)*9;
            #pragma unroll
            for (int k = 0; k < 9; ++k)
                acc[j] = fma((double)wj[k], v[k], acc[j]);
        }
    }
    #pragma unroll
    for (int j = 0; j < NOUT; ++j)
        y1p[(((size_t)z*BB + b)*NOUT + j)*HWW + p] = acc[j];
}

// Reduce partials + bias -> y1. Grid: (B,5) x 256.
__global__ __launch_bounds__(256) void readout_conv_reduce(
    const double* __restrict__ y1p,   // [RCH,B,10,1156]
    const float* __restrict__ b_r1,   // [10]
    double* __restrict__ y1)          // [B,10,1156]
{
    const int b = blockIdx.x;
    const int p = blockIdx.y * 256 + threadIdx.x;
    if (p >= HWW) return;
    #pragma unroll
    for (int j = 0; j < NOUT; ++j) {
        double s = (double)b_r1[j];
        #pragma unroll
        for (int z = 0; z < RCH; ++z)
            s += y1p[(((size_t)z*BB + b)*NOUT + j)*HWW + p];
        y1[((size_t)b*NOUT + j)*HWW + p] = s;
    }
}

// ---------------------------------------------------------------------------
// FC + softmax in fp64. Grid: B blocks.
// ---------------------------------------------------------------------------
__global__ __launch_bounds__(256) void readout_fc(
    const double* __restrict__ y1,    // [B, 10*1156]
    const float* __restrict__ w_r2,   // [10, 11560]
    const float* __restrict__ b_r2,   // [10]
    float* __restrict__ out)          // [B,10]
{
    const int b = blockIdx.x;
    const double* yb = y1 + (size_t)b*NOUT*HWW;

    double acc[NOUT];
    #pragma unroll
    for (int o = 0; o < NOUT; ++o) acc[o] = 0.0;

    for (int i = threadIdx.x; i < NOUT*HWW; i += 256) {
        const double v = yb[i];
        #pragma unroll
        for (int o = 0; o < NOUT; ++o)
            acc[o] = fma(v, (double)w_r2[(size_t)o*NOUT*HWW + i], acc[o]);
    }

    const int lane = threadIdx.x & 63;
    const int wv   = threadIdx.x >> 6;
    __shared__ double wsum[4][NOUT];

    #pragma unroll
    for (int o = 0; o < NOUT; ++o) {
        double v = acc[o];
        #pragma unroll
        for (int off = 32; off > 0; off >>= 1) v += __shfl_down(v, off);
        if (lane == 0) wsum[wv][o] = v;
    }
    __syncthreads();

    if (threadIdx.x == 0) {
        double s[NOUT];
        double mx = -1e300;
        #pragma unroll
        for (int o = 0; o < NOUT; ++o) {
            s[o] = wsum[0][o] + wsum[1][o] + wsum[2][o] + wsum[3][o]
                 + (double)b_r2[o];
            mx = fmax(mx, s[o]);
        }
        double den = 0.0;
        #pragma unroll
        for (int o = 0; o < NOUT; ++o) { s[o] = exp(s[o] - mx); den += s[o]; }
        #pragma unroll
        for (int o = 0; o < NOUT; ++o) out[b*NOUT + o] = (float)(s[o] / den);
    }
}

// ---------------------------------------------------------------------------
extern "C" void kernel_launch(void* const* d_in, const int* in_sizes, int n_in,
                              void* d_out, int out_size, void* d_ws, size_t ws_size,
                              hipStream_t stream)
{
    const float* x     = (const float*)d_in[0];
    const float* w_in  = (const float*)d_in[1];
    const float* b_in  = (const float*)d_in[2];
    const float* w_rec = (const float*)d_in[3];
    const float* b_rec = (const float*)d_in[4];
    const float* w_r1  = (const float*)d_in[5];
    const float* b_r1  = (const float*)d_in[6];
    const float* w_r2  = (const float*)d_in[7];
    const float* b_r2  = (const float*)d_in[8];

    float* out     = (float*)d_out;          // [32,10]
    float* spk_rec = out + BB*NOUT;          // [48,32,64,34,34]

    // Workspace: syn|mem|pad0(u8)|pad1(u8)|partsum contiguous -> one memset.
    const size_t n_state = (size_t)BB*CR*HWW;       // 2,367,488
    const size_t n_pad   = (size_t)BB*CR*PHWP;      // 2,654,208 (u8 bytes)
    const size_t n_part  = (size_t)NP*BB*CR*HWW;    // 7,102,464 bytes (uint8)
    const size_t n_y1    = (size_t)BB*NOUT*HWW;     // 369,920

    char* ws = (char*)d_ws;
    float*         syn     = (float*)ws;             ws += n_state*4;
    float*         mem     = (float*)ws;             ws += n_state*4;
    unsigned char* pad0    = (unsigned char*)ws;     ws += n_pad;
    unsigned char* pad1    = (unsigned char*)ws;     ws += n_pad;
    unsigned char* partsum = (unsigned char*)ws;     ws += n_part;
    double*        y1      = (double*)ws;            ws += n_y1*8;
    double*        y1p     = (double*)ws;            ws += (size_t)RCH*n_y1*8;
    float*         wiT     = (float*)ws;             ws += 18*64*4;
    float*         wrT     = (float*)ws;             ws += 576*64*4;
    // y1 byte offset = n_state*8 + 2*n_pad + n_part = 31,350,784 (8B-aligned)

    const size_t zero_bytes = n_state*8 + 2*n_pad + n_part;
    hipMemsetAsync(d_ws, 0, zero_bytes, stream);

    transpose_weights<<<(576*64 + 255)/256, 256, 0, stream>>>(
        w_in, w_rec, wiT, wrT);

    for (int t = 0; t < TT; ++t) {
        const unsigned char* rd = (t & 1) ? pad1 : pad0; // t=0 reads zeroed
        unsigned char*       wr = (t & 1) ? pad0 : pad1;
        step_kernel<<<dim3(BB, 5, CR/OG), 256, 0, stream>>>(
            x, wiT, b_in, wrT, b_rec,
            rd, wr, syn, mem, spk_rec, partsum, t);
    }

    readout_conv_part<<<dim3(BB, 5, RCH), 256, 0, stream>>>(partsum, w_r1, y1p);
    readout_conv_reduce<<<dim3(BB, 5), 256, 0, stream>>>(y1p, b_r1, y1);
    readout_fc<<<BB, 256, 0, stream>>>(y1, w_r2, b_r2, out);
}